// Round 1
// baseline (719.573 us; speedup 1.0000x reference)
//
#include <hip/hip_runtime.h>
#include <cstdint>
#include <cstddef>

#define BATCH 8
#define HH 56
#define WW 56
#define HWSZ 3136      // HH*WW
#define P4SZ 784       // HWSZ/4
#define JC 49          // j-chunks per batch in kglobal
#define JCH 64         // rows per chunk (49*64 = 3136)

// ---- monotone float <-> uint mapping for atomicMax on floats ----
__device__ __forceinline__ unsigned fmap(float f) {
    unsigned u = __float_as_uint(f);
    return (u & 0x80000000u) ? ~u : (u | 0x80000000u);
}
__device__ __forceinline__ float funmap(unsigned u) {
    if (u == 0u) return -INFINITY;   // sentinel (memset value, never produced by fmap of a real)
    return (u & 0x80000000u) ? __uint_as_float(u ^ 0x80000000u) : __uint_as_float(~u);
}

__device__ __forceinline__ void fmax4(float4& m, float4 x, float s) {
    m.x = fmaxf(m.x, x.x * s);
    m.y = fmaxf(m.y, x.y * s);
    m.z = fmaxf(m.z, x.z * s);
    m.w = fmaxf(m.w, x.w * s);
}

// ============================================================================
// Kernel 1 — global branch: acc_g[b][ch][p] = max_j sim[b][j][p]*seg[b][ch][j]
// Grid: BATCH*JC blocks of 256. Each block: one b, 64 rows of j, all 784
// float4 columns (threads own cols t, t+256, t+512, and t+768 for t<16).
// ============================================================================
__global__ __launch_bounds__(256) void kglobal(const float4* __restrict__ sim4,
                                               const float* __restrict__ seg,
                                               unsigned* __restrict__ acc) {
    const int blk = blockIdx.x;
    const int b  = blk / JC;
    const int j0 = (blk % JC) * JCH;
    const int t  = threadIdx.x;

    __shared__ float s0[JCH], s1[JCH];
    if (t < JCH)            s0[t]        = seg[(size_t)(b * 2 + 0) * HWSZ + j0 + t];
    else if (t < 2 * JCH)   s1[t - JCH]  = seg[(size_t)(b * 2 + 1) * HWSZ + j0 + (t - JCH)];
    __syncthreads();

    const float4 NEG4 = make_float4(-INFINITY, -INFINITY, -INFINITY, -INFINITY);
    float4 a0[4], a1[4];
    #pragma unroll
    for (int i = 0; i < 4; ++i) { a0[i] = NEG4; a1[i] = NEG4; }

    const float4* base = sim4 + (size_t)(b * HWSZ + j0) * P4SZ;
    const bool tail = (t < 16);

    for (int j = 0; j < JCH; ++j) {
        const float v0 = s0[j], v1 = s1[j];
        const float4* row = base + (size_t)j * P4SZ;
        #pragma unroll
        for (int i = 0; i < 3; ++i) {
            float4 x = row[t + 256 * i];
            fmax4(a0[i], x, v0);
            fmax4(a1[i], x, v1);
        }
        if (tail) {
            float4 x = row[768 + t];
            fmax4(a0[3], x, v0);
            fmax4(a1[3], x, v1);
        }
    }

    unsigned* g0 = acc + (size_t)(b * 2 + 0) * HWSZ;
    unsigned* g1 = acc + (size_t)(b * 2 + 1) * HWSZ;
    #pragma unroll
    for (int i = 0; i < 3; ++i) {
        const int p = 4 * (t + 256 * i);
        atomicMax(&g0[p + 0], fmap(a0[i].x)); atomicMax(&g0[p + 1], fmap(a0[i].y));
        atomicMax(&g0[p + 2], fmap(a0[i].z)); atomicMax(&g0[p + 3], fmap(a0[i].w));
        atomicMax(&g1[p + 0], fmap(a1[i].x)); atomicMax(&g1[p + 1], fmap(a1[i].y));
        atomicMax(&g1[p + 2], fmap(a1[i].z)); atomicMax(&g1[p + 3], fmap(a1[i].w));
    }
    if (tail) {
        const int p = 4 * (768 + t);
        atomicMax(&g0[p + 0], fmap(a0[3].x)); atomicMax(&g0[p + 1], fmap(a0[3].y));
        atomicMax(&g0[p + 2], fmap(a0[3].z)); atomicMax(&g0[p + 3], fmap(a0[3].w));
        atomicMax(&g1[p + 0], fmap(a1[3].x)); atomicMax(&g1[p + 1], fmap(a1[3].y));
        atomicMax(&g1[p + 2], fmap(a1[3].z)); atomicMax(&g1[p + 3], fmap(a1[3].w));
    }
}

// ============================================================================
// Kernel 2 — local branch. One wave per (b,j) row of prev_sim (3136 floats,
// kept in registers: 12 float4 + 1 scalar per lane). Computes row min and
// row top-4 (values), wave-merges, then atomically maxes the >=cut elements
// (scaled per channel) into acc_l and the scale*min term into Ml.
// ============================================================================
__global__ __launch_bounds__(256) void klocal(const float* __restrict__ simf,
                                              const float* __restrict__ seg,
                                              unsigned* __restrict__ acc,
                                              unsigned* __restrict__ Ml) {
    const int wave = (blockIdx.x << 2) | (threadIdx.x >> 6);
    const int lane = threadIdx.x & 63;
    const int b = wave / HWSZ;
    const int j = wave - b * HWSZ;

    const float* rowf = simf + (size_t)wave * HWSZ;
    const float4* row4 = (const float4*)rowf;

    float4 x[12];
    #pragma unroll
    for (int k = 0; k < 12; ++k) x[k] = row4[k * 64 + lane];
    const float xs = rowf[3072 + lane];

    float mn = INFINITY;
    float t0 = -INFINITY, t1 = -INFINITY, t2 = -INFINITY, t3 = -INFINITY;

    // branchless sorted insert (keeps t0>=t1>=t2>=t3 = top-4 of inserted set)
    #define INS(v) do { \
        float _v = (v); \
        float _r0 = fmaxf(t0, _v), _s0 = fminf(t0, _v); \
        float _r1 = fmaxf(t1, _s0), _s1 = fminf(t1, _s0); \
        float _r2 = fmaxf(t2, _s1), _s2 = fminf(t2, _s1); \
        float _r3 = fmaxf(t3, _s2); \
        t0 = _r0; t1 = _r1; t2 = _r2; t3 = _r3; } while (0)

    #pragma unroll
    for (int k = 0; k < 12; ++k) {
        mn = fminf(mn, fminf(fminf(x[k].x, x[k].y), fminf(x[k].z, x[k].w)));
        INS(x[k].x); INS(x[k].y); INS(x[k].z); INS(x[k].w);
    }
    mn = fminf(mn, xs);
    INS(xs);

    // wave butterfly: all lanes converge to row min and row top-4
    #pragma unroll
    for (int off = 32; off; off >>= 1) {
        mn = fminf(mn, __shfl_xor(mn, off));
        float o0 = __shfl_xor(t0, off);
        float o1 = __shfl_xor(t1, off);
        float o2 = __shfl_xor(t2, off);
        float o3 = __shfl_xor(t3, off);
        INS(o0); INS(o1); INS(o2); INS(o3);
    }
    #undef INS

    const float cut = t3;   // 4th largest raw value of the row
    const float sc0 = seg[(size_t)(b * 2 + 0) * HWSZ + j];
    const float sc1 = seg[(size_t)(b * 2 + 1) * HWSZ + j];

    unsigned* l0 = acc + (size_t)(b * 2 + 0) * HWSZ;
    unsigned* l1 = acc + (size_t)(b * 2 + 1) * HWSZ;

    #pragma unroll
    for (int k = 0; k < 12; ++k) {
        const int pb = (k * 64 + lane) * 4;
        if (x[k].x >= cut) { atomicMax(&l0[pb + 0], fmap(x[k].x * sc0)); atomicMax(&l1[pb + 0], fmap(x[k].x * sc1)); }
        if (x[k].y >= cut) { atomicMax(&l0[pb + 1], fmap(x[k].y * sc0)); atomicMax(&l1[pb + 1], fmap(x[k].y * sc1)); }
        if (x[k].z >= cut) { atomicMax(&l0[pb + 2], fmap(x[k].z * sc0)); atomicMax(&l1[pb + 2], fmap(x[k].z * sc1)); }
        if (x[k].w >= cut) { atomicMax(&l0[pb + 3], fmap(x[k].w * sc0)); atomicMax(&l1[pb + 3], fmap(x[k].w * sc1)); }
    }
    if (xs >= cut) {
        const int p = 3072 + lane;
        atomicMax(&l0[p], fmap(xs * sc0));
        atomicMax(&l1[p], fmap(xs * sc1));
    }

    // per-row min term: block-reduce (4 waves, all same b) then one atomic
    __shared__ float mred[8];
    if (lane == 0) {
        const int w = threadIdx.x >> 6;
        mred[w * 2 + 0] = mn * sc0;
        mred[w * 2 + 1] = mn * sc1;
    }
    __syncthreads();
    if (threadIdx.x == 0) {
        float m0 = fmaxf(fmaxf(mred[0], mred[2]), fmaxf(mred[4], mred[6]));
        float m1 = fmaxf(fmaxf(mred[1], mred[3]), fmaxf(mred[5], mred[7]));
        atomicMax(&Ml[b * 2 + 0], fmap(m0));
        atomicMax(&Ml[b * 2 + 1], fmap(m1));
    }
}

// ============================================================================
// Kernel 3 — finalize: unmap accumulators, combine local min-term, write out
// out layout: (B, 4, H, W) channels = [bg_g, fg_g, bg_l, fg_l]
// ============================================================================
__global__ __launch_bounds__(256) void kfinal(const unsigned* __restrict__ accg,
                                              const unsigned* __restrict__ accl,
                                              const unsigned* __restrict__ Ml,
                                              float* __restrict__ out) {
    const int tid = blockIdx.x * 256 + threadIdx.x;
    if (tid >= BATCH * HWSZ) return;
    const int b = tid / HWSZ;
    const int p = tid - b * HWSZ;

    const float g0 = funmap(accg[(size_t)(b * 2 + 0) * HWSZ + p]);
    const float g1 = funmap(accg[(size_t)(b * 2 + 1) * HWSZ + p]);
    const float M0 = funmap(Ml[b * 2 + 0]);
    const float M1 = funmap(Ml[b * 2 + 1]);
    const float l0 = fmaxf(M0, funmap(accl[(size_t)(b * 2 + 0) * HWSZ + p]));
    const float l1 = fmaxf(M1, funmap(accl[(size_t)(b * 2 + 1) * HWSZ + p]));

    float* ob = out + (size_t)b * 4 * HWSZ;
    ob[0 * HWSZ + p] = g0;
    ob[1 * HWSZ + p] = g1;
    ob[2 * HWSZ + p] = l0;
    ob[3 * HWSZ + p] = l1;
}

extern "C" void kernel_launch(void* const* d_in, const int* in_sizes, int n_in,
                              void* d_out, int out_size, void* d_ws, size_t ws_size,
                              hipStream_t stream) {
    const float* init_sim = (const float*)d_in[0];
    const float* prev_sim = (const float*)d_in[1];
    const float* init_seg = (const float*)d_in[2];
    const float* prev_seg = (const float*)d_in[3];
    float* out = (float*)d_out;

    unsigned* accg = (unsigned*)d_ws;                       // BATCH*2*HWSZ
    unsigned* accl = accg + (size_t)BATCH * 2 * HWSZ;       // BATCH*2*HWSZ
    unsigned* Ml   = accl + (size_t)BATCH * 2 * HWSZ;       // BATCH*2
    const size_t clear_bytes = ((size_t)BATCH * 2 * HWSZ * 2 + BATCH * 2) * sizeof(unsigned);

    hipMemsetAsync(d_ws, 0, clear_bytes, stream);

    kglobal<<<BATCH * JC, 256, 0, stream>>>((const float4*)init_sim, init_seg, accg);
    klocal<<<(BATCH * HWSZ) / 4, 256, 0, stream>>>(prev_sim, prev_seg, accl, Ml);
    kfinal<<<(BATCH * HWSZ + 255) / 256, 256, 0, stream>>>(accg, accl, Ml, out);
}

// Round 2
// 710.169 us; speedup vs baseline: 1.0132x; 1.0132x over previous
//
#include <hip/hip_runtime.h>
#include <cstdint>
#include <cstddef>

#define BATCH 8
#define HH 56
#define WW 56
#define HWSZ 3136      // HH*WW
#define P4SZ 784       // HWSZ/4
#define CPB 4          // float4 columns per kglobal block
#define CBLK (P4SZ / CPB)   // 196 column-blocks per batch

// ---- monotone float <-> uint mapping for atomicMax on floats ----
__device__ __forceinline__ unsigned fmap(float f) {
    unsigned u = __float_as_uint(f);
    return (u & 0x80000000u) ? ~u : (u | 0x80000000u);
}
__device__ __forceinline__ float funmap(unsigned u) {
    if (u == 0u) return -INFINITY;   // memset sentinel (never produced by fmap)
    return (u & 0x80000000u) ? __uint_as_float(u ^ 0x80000000u) : __uint_as_float(~u);
}

__device__ __forceinline__ void fmax4(float4& m, float4 x, float s) {
    m.x = fmaxf(m.x, x.x * s);
    m.y = fmaxf(m.y, x.y * s);
    m.z = fmaxf(m.z, x.z * s);
    m.w = fmaxf(m.w, x.w * s);
}

// ============================================================================
// Kernel 1 — global branch, atomic-free.
// out[b][ch][p] = max_j sim[b][j][p] * seg[b][ch][j],  ch in {0,1}
// Grid: BATCH*CBLK = 1568 blocks of 256 (6.1 blocks/CU). Each block owns one
// batch and a 4-float4 column stripe; thread t: col = t&3, rowoff = t>>2,
// loops 49 rows (stride 64). seg staged in LDS. Shuffle+LDS max reduction,
// direct float stores into d_out (no workspace, no atomics).
// ============================================================================
__global__ __launch_bounds__(256) void kglobal(const float4* __restrict__ sim4,
                                               const float* __restrict__ seg,
                                               float* __restrict__ out) {
    __shared__ float s0[HWSZ], s1[HWSZ];   // 25 KB
    __shared__ float red[4][CPB][8];       // 512 B

    const int blk = blockIdx.x;
    const int b  = blk / CBLK;
    const int cg = blk - b * CBLK;
    const int c0 = cg * CPB;
    const int t  = threadIdx.x;

    const float* seg0 = seg + (size_t)(b * 2 + 0) * HWSZ;
    const float* seg1 = seg + (size_t)(b * 2 + 1) * HWSZ;
    for (int i = t; i < HWSZ; i += 256) { s0[i] = seg0[i]; s1[i] = seg1[i]; }
    __syncthreads();

    const int col    = t & 3;
    const int rowoff = t >> 2;   // 0..63

    const float4* base = sim4 + (size_t)b * HWSZ * P4SZ + (c0 + col);

    float4 a0 = make_float4(-INFINITY, -INFINITY, -INFINITY, -INFINITY);
    float4 a1 = a0;

    #pragma unroll 7
    for (int i = 0; i < 49; ++i) {
        const int r = rowoff + (i << 6);
        float4 x = base[(size_t)r * P4SZ];
        const float v0 = s0[r], v1 = s1[r];
        fmax4(a0, x, v0);
        fmax4(a1, x, v1);
    }

    // butterfly over lane bits 2..5 (rowoff-within-wave); col bits preserved
    #pragma unroll
    for (int off = 4; off <= 32; off <<= 1) {
        a0.x = fmaxf(a0.x, __shfl_xor(a0.x, off));
        a0.y = fmaxf(a0.y, __shfl_xor(a0.y, off));
        a0.z = fmaxf(a0.z, __shfl_xor(a0.z, off));
        a0.w = fmaxf(a0.w, __shfl_xor(a0.w, off));
        a1.x = fmaxf(a1.x, __shfl_xor(a1.x, off));
        a1.y = fmaxf(a1.y, __shfl_xor(a1.y, off));
        a1.z = fmaxf(a1.z, __shfl_xor(a1.z, off));
        a1.w = fmaxf(a1.w, __shfl_xor(a1.w, off));
    }

    const int w = t >> 6, lane = t & 63;
    if (lane < 4) {
        red[w][lane][0] = a0.x; red[w][lane][1] = a0.y;
        red[w][lane][2] = a0.z; red[w][lane][3] = a0.w;
        red[w][lane][4] = a1.x; red[w][lane][5] = a1.y;
        red[w][lane][6] = a1.z; red[w][lane][7] = a1.w;
    }
    __syncthreads();

    if (t < 32) {
        const int cc = t & 3, comp = t >> 2;      // comp 0..7
        const float v = fmaxf(fmaxf(red[0][cc][comp], red[1][cc][comp]),
                              fmaxf(red[2][cc][comp], red[3][cc][comp]));
        const int ch = comp >> 2, sub = comp & 3; // ch 0..1, sub 0..3
        out[(size_t)b * 4 * HWSZ + (size_t)ch * HWSZ + (c0 + cc) * 4 + sub] = v;
    }
}

// ============================================================================
// Kernel 2 — local branch. One wave per (b,j) row of prev_sim (3136 floats,
// kept in registers: 12 float4 + 1 scalar per lane). Computes row min and
// row top-4, wave-merges, then atomically maxes the >=cut elements (scaled
// per channel) into acc and the scale*min term into Ml.
// ============================================================================
__global__ __launch_bounds__(256) void klocal(const float* __restrict__ simf,
                                              const float* __restrict__ seg,
                                              unsigned* __restrict__ acc,
                                              unsigned* __restrict__ Ml) {
    const int wave = (blockIdx.x << 2) | (threadIdx.x >> 6);
    const int lane = threadIdx.x & 63;
    const int b = wave / HWSZ;
    const int j = wave - b * HWSZ;

    const float* rowf = simf + (size_t)wave * HWSZ;
    const float4* row4 = (const float4*)rowf;

    float4 x[12];
    #pragma unroll
    for (int k = 0; k < 12; ++k) x[k] = row4[k * 64 + lane];
    const float xs = rowf[3072 + lane];

    float mn = INFINITY;
    float t0 = -INFINITY, t1 = -INFINITY, t2 = -INFINITY, t3 = -INFINITY;

    // branchless sorted insert (keeps t0>=t1>=t2>=t3 = top-4 of inserted set)
    #define INS(v) do { \
        float _v = (v); \
        float _r0 = fmaxf(t0, _v), _s0 = fminf(t0, _v); \
        float _r1 = fmaxf(t1, _s0), _s1 = fminf(t1, _s0); \
        float _r2 = fmaxf(t2, _s1), _s2 = fminf(t2, _s1); \
        float _r3 = fmaxf(t3, _s2); \
        t0 = _r0; t1 = _r1; t2 = _r2; t3 = _r3; } while (0)

    #pragma unroll
    for (int k = 0; k < 12; ++k) {
        mn = fminf(mn, fminf(fminf(x[k].x, x[k].y), fminf(x[k].z, x[k].w)));
        INS(x[k].x); INS(x[k].y); INS(x[k].z); INS(x[k].w);
    }
    mn = fminf(mn, xs);
    INS(xs);

    // wave butterfly: all lanes converge to row min and row top-4
    #pragma unroll
    for (int off = 32; off; off >>= 1) {
        mn = fminf(mn, __shfl_xor(mn, off));
        float o0 = __shfl_xor(t0, off);
        float o1 = __shfl_xor(t1, off);
        float o2 = __shfl_xor(t2, off);
        float o3 = __shfl_xor(t3, off);
        INS(o0); INS(o1); INS(o2); INS(o3);
    }
    #undef INS

    const float cut = t3;   // 4th largest raw value of the row
    const float sc0 = seg[(size_t)(b * 2 + 0) * HWSZ + j];
    const float sc1 = seg[(size_t)(b * 2 + 1) * HWSZ + j];

    unsigned* l0 = acc + (size_t)(b * 2 + 0) * HWSZ;
    unsigned* l1 = acc + (size_t)(b * 2 + 1) * HWSZ;

    #pragma unroll
    for (int k = 0; k < 12; ++k) {
        const int pb = (k * 64 + lane) * 4;
        if (x[k].x >= cut) { atomicMax(&l0[pb + 0], fmap(x[k].x * sc0)); atomicMax(&l1[pb + 0], fmap(x[k].x * sc1)); }
        if (x[k].y >= cut) { atomicMax(&l0[pb + 1], fmap(x[k].y * sc0)); atomicMax(&l1[pb + 1], fmap(x[k].y * sc1)); }
        if (x[k].z >= cut) { atomicMax(&l0[pb + 2], fmap(x[k].z * sc0)); atomicMax(&l1[pb + 2], fmap(x[k].z * sc1)); }
        if (x[k].w >= cut) { atomicMax(&l0[pb + 3], fmap(x[k].w * sc0)); atomicMax(&l1[pb + 3], fmap(x[k].w * sc1)); }
    }
    if (xs >= cut) {
        const int p = 3072 + lane;
        atomicMax(&l0[p], fmap(xs * sc0));
        atomicMax(&l1[p], fmap(xs * sc1));
    }

    // per-row min term: block-reduce (4 waves, all same b) then one atomic
    __shared__ float mred[8];
    if (lane == 0) {
        const int w = threadIdx.x >> 6;
        mred[w * 2 + 0] = mn * sc0;
        mred[w * 2 + 1] = mn * sc1;
    }
    __syncthreads();
    if (threadIdx.x == 0) {
        float m0 = fmaxf(fmaxf(mred[0], mred[2]), fmaxf(mred[4], mred[6]));
        float m1 = fmaxf(fmaxf(mred[1], mred[3]), fmaxf(mred[5], mred[7]));
        atomicMax(&Ml[b * 2 + 0], fmap(m0));
        atomicMax(&Ml[b * 2 + 1], fmap(m1));
    }
}

// ============================================================================
// Kernel 3 — finalize local channels only: unmap accumulator, combine
// min-term, write out[b][2][p] / out[b][3][p].
// ============================================================================
__global__ __launch_bounds__(256) void kfinal(const unsigned* __restrict__ accl,
                                              const unsigned* __restrict__ Ml,
                                              float* __restrict__ out) {
    const int tid = blockIdx.x * 256 + threadIdx.x;
    if (tid >= BATCH * HWSZ) return;
    const int b = tid / HWSZ;
    const int p = tid - b * HWSZ;

    const float M0 = funmap(Ml[b * 2 + 0]);
    const float M1 = funmap(Ml[b * 2 + 1]);
    const float l0 = fmaxf(M0, funmap(accl[(size_t)(b * 2 + 0) * HWSZ + p]));
    const float l1 = fmaxf(M1, funmap(accl[(size_t)(b * 2 + 1) * HWSZ + p]));

    float* ob = out + (size_t)b * 4 * HWSZ;
    ob[2 * HWSZ + p] = l0;
    ob[3 * HWSZ + p] = l1;
}

extern "C" void kernel_launch(void* const* d_in, const int* in_sizes, int n_in,
                              void* d_out, int out_size, void* d_ws, size_t ws_size,
                              hipStream_t stream) {
    const float* init_sim = (const float*)d_in[0];
    const float* prev_sim = (const float*)d_in[1];
    const float* init_seg = (const float*)d_in[2];
    const float* prev_seg = (const float*)d_in[3];
    float* out = (float*)d_out;

    unsigned* accl = (unsigned*)d_ws;                       // BATCH*2*HWSZ
    unsigned* Ml   = accl + (size_t)BATCH * 2 * HWSZ;       // BATCH*2
    const size_t clear_bytes = ((size_t)BATCH * 2 * HWSZ + BATCH * 2) * sizeof(unsigned);

    hipMemsetAsync(d_ws, 0, clear_bytes, stream);

    kglobal<<<BATCH * CBLK, 256, 0, stream>>>((const float4*)init_sim, init_seg, out);
    klocal<<<(BATCH * HWSZ) / 4, 256, 0, stream>>>(prev_sim, prev_seg, accl, Ml);
    kfinal<<<(BATCH * HWSZ + 255) / 256, 256, 0, stream>>>(accl, Ml, out);
}